// Round 12
// baseline (279.149 us; speedup 1.0000x reference)
//
#include <hip/hip_runtime.h>

// Problem constants (fixed by reference)
#define IN_DIM  256
#define HID_DIM 256
#define H2_DIM  128
#define EMB_DIM 64
#define K_CODES 4096
#define EPS_BN  1e-5f

// History: R5 hi/lo-split MFMA argmin 205us. R9 barrier-free stream 126.
// R13 global_load_lds DMA + dbuf (128-code chunks, 64KB LDS) 119us. R15
// FAILED (absmax 1156): folding -nv into MFMA C-init reorders score
// rounding -> flips near-ties in the DISCRETE argmin. RULE: never reorder
// the score arithmetic (acc from 0, subtract nv in fp32 after, acc0+acc1
// pairing). R16: R13 verbatim + encoder h2-aliasing: 267us BEST (argmin
// 116.7). R17: norms-in-LDS NULL (119.1) -> norms VMEM read was never the
// wall; reverted.
// R18: argmin instruction arithmetic (VALU ~41k + MFMA ~25k cyc/SIMD vs
// 285k measured) shows it is LATENCY-bound at 2 waves/SIMD, and LDS 64KB
// is what caps it (VGPR 108 allows 16 waves/CU). Fix: 64-code chunks ->
// 16KB buffers, dbuf = 32KB -> 4 blocks/CU = 4 waves/SIMD, same DMA
// schedule. Fragment gather uses per-lane GLOBAL addresses (LDS dest
// stays lane-linear, as required). Column visit order, operand values,
// MFMA sequence, compare trajectory bit-identical -> absmax 0.

typedef _Float16 f16;
typedef _Float16 f16x4 __attribute__((ext_vector_type(4)));
typedef _Float16 f16x8 __attribute__((ext_vector_type(8)));
typedef float    f32x16 __attribute__((ext_vector_type(16)));

// ---------------------------------------------------------------------------
// Kernel 0a: half squared norms of codebook rows: norms[c] = 0.5*||e_c||^2
// ---------------------------------------------------------------------------
__global__ __launch_bounds__(256) void k_norms(const float* __restrict__ cb,
                                               float* __restrict__ norms) {
    int c = blockIdx.x * 256 + threadIdx.x;
    const float4* row = reinterpret_cast<const float4*>(cb + (size_t)c * EMB_DIM);
    float s = 0.f;
#pragma unroll
    for (int i = 0; i < EMB_DIM / 4; ++i) {
        float4 v = row[i];
        s += v.x * v.x + v.y * v.y + v.z * v.z + v.w * v.w;
    }
    norms[c] = 0.5f * s;
}

// ---------------------------------------------------------------------------
// Kernel 0b: fragment-major hi/lo packer.
// A fragment = 512 f16 = what one wave loads for one (k16-step, 32-col-tile):
//   P[f*512 + l*8 + j] = W[ct*32 + (l&31)][k0 + (l>>5)*8 + j]
// f16x8 unit index t (one thread each), 46080 total:
//   [0,8192)      W1 [256][256]: f = kst*8 + ct   (kst<16, ct<8)
//   [8192,12288)  W2 [128][256]: f = kst*4 + ct   (kst<16, ct<4)
//   [12288,13312) W3 [ 64][128]: f = ks*2  + ct   (ks<8, ct<2)
//   [13312,46080) cb [4096][64]: f = (ch*4+ks)*4+ct (ch<32, ks<4, ct<4)
// ---------------------------------------------------------------------------
__global__ __launch_bounds__(256) void k_prep(
    const float* __restrict__ W1, const float* __restrict__ W2,
    const float* __restrict__ W3, const float* __restrict__ cb,
    f16* __restrict__ p1h, f16* __restrict__ p1l,
    f16* __restrict__ p2h, f16* __restrict__ p2l,
    f16* __restrict__ p3h, f16* __restrict__ p3l,
    f16* __restrict__ cfh, f16* __restrict__ cfl) {
    int t = blockIdx.x * 256 + threadIdx.x;   // < 46080
    const float* src; f16 *dh, *dl; int tt, row, k0, K;
    if (t < 8192) {
        tt = t; int f = tt >> 6, l = tt & 63;
        int ct = f & 7, kst = f >> 3;
        row = ct * 32 + (l & 31); k0 = kst * 16 + (l >> 5) * 8;
        src = W1; K = IN_DIM; dh = p1h; dl = p1l;
    } else if (t < 12288) {
        tt = t - 8192; int f = tt >> 6, l = tt & 63;
        int ct = f & 3, kst = f >> 2;
        row = ct * 32 + (l & 31); k0 = kst * 16 + (l >> 5) * 8;
        src = W2; K = HID_DIM; dh = p2h; dl = p2l;
    } else if (t < 13312) {
        tt = t - 12288; int f = tt >> 6, l = tt & 63;
        int ct = f & 1, ks = f >> 1;
        row = ct * 32 + (l & 31); k0 = ks * 16 + (l >> 5) * 8;
        src = W3; K = H2_DIM; dh = p3h; dl = p3l;
    } else {
        tt = t - 13312; int f = tt >> 6, l = tt & 63;
        int ct = f & 3, ks = (f >> 2) & 3, ch = f >> 4;
        row = ch * 128 + ct * 32 + (l & 31); k0 = ks * 16 + (l >> 5) * 8;
        src = cb; K = EMB_DIM; dh = cfh; dl = cfl;
    }
    const float* s = src + (size_t)row * K + k0;
    f16x8 hv, lv;
#pragma unroll
    for (int j = 0; j < 8; ++j) {
        float v = s[j];
        f16 h = (f16)v;
        hv[j] = h;
        lv[j] = (f16)(v - (float)h);
    }
    *(f16x8*)(dh + (size_t)tt * 8) = hv;
    *(f16x8*)(dl + (size_t)tt * 8) = lv;
}

// ---------------------------------------------------------------------------
// Kernel 1: fused MFMA encoder. 32 rows/block, 256 threads (4 waves).
// All GEMMs as v_mfma_f32_32x32x16_f16, 3 passes (hh, lh, hl) per k-step.
// A-frags from LDS; B-frags streamed from fragment-major global with 1-deep
// register prefetch. h2 planes ALIASED into region A after stage-2 k-loop
// (extra barrier; bit-identical values) -> LDS 33KB -> 4 blocks/CU.
// LDS map: region A [0,16896) f16: xh/h1h@0, xl/h1l@8448 (stride 264);
//          after stage-2 k-loop: h2h@0, h2l@4352 (stride 136).
// (Unchanged from R16 for attribution.)
// ---------------------------------------------------------------------------
__global__ __launch_bounds__(256) void k_encoder_mfma(
    const float* __restrict__ x,
    const f16* __restrict__ p1h, const f16* __restrict__ p1l,
    const f16* __restrict__ p2h, const f16* __restrict__ p2l,
    const f16* __restrict__ p3h, const f16* __restrict__ p3l,
    const float* __restrict__ b1,
    const float* __restrict__ gm, const float* __restrict__ bt,
    const float* __restrict__ mu, const float* __restrict__ vr,
    const float* __restrict__ b2, const float* __restrict__ b3,
    f16* __restrict__ Zh, f16* __restrict__ Zl) {
    __shared__ __align__(16) f16 sm[16896];   // 33 KB -> 4 blocks/CU
    const int tid  = threadIdx.x;
    const int lane = tid & 63;
    const int w    = tid >> 6;
    const int ln31 = lane & 31;
    const int q    = lane >> 5;
    const int r0   = blockIdx.x * 32;

    // ---- stage x [32 rows][256 k] fp32 -> hi/lo f16 planes, once ----------
#pragma unroll
    for (int it = 0; it < 8; ++it) {
        int i = it * 256 + tid;              // float4 id, 2048 total
        int row = i >> 6, c4 = (i & 63) * 4;
        float4 v = *reinterpret_cast<const float4*>(
            x + (size_t)(r0 + row) * IN_DIM + c4);
        f16x4 hv, lv;
        hv[0] = (f16)v.x; lv[0] = (f16)(v.x - (float)hv[0]);
        hv[1] = (f16)v.y; lv[1] = (f16)(v.y - (float)hv[1]);
        hv[2] = (f16)v.z; lv[2] = (f16)(v.z - (float)hv[2]);
        hv[3] = (f16)v.w; lv[3] = (f16)(v.w - (float)hv[3]);
        *(f16x4*)(sm + row * 264 + c4)        = hv;
        *(f16x4*)(sm + 8448 + row * 264 + c4) = lv;
    }
    __syncthreads();

    // ================= Stage 1: h1 = BN+ReLU(x @ W1^T) ======================
    f32x16 acc1a = {};
    f32x16 acc1b = {};
    {
        const f16* q1h = p1h + (size_t)(2 * w) * 512 + lane * 8;
        const f16* q1l = p1l + (size_t)(2 * w) * 512 + lane * 8;
        f16x8 bh0 = *(const f16x8*)(q1h);
        f16x8 bh1 = *(const f16x8*)(q1h + 512);
        f16x8 bl0 = *(const f16x8*)(q1l);
        f16x8 bl1 = *(const f16x8*)(q1l + 512);
#pragma unroll 2
        for (int kst = 0; kst < 16; ++kst) {
            f16x8 ch0 = bh0, ch1 = bh1, cl0 = bl0, cl1 = bl1;
            int kn = (kst + 1) & 15;  // wrap: last prefetch redundant, harmless
            bh0 = *(const f16x8*)(q1h + (size_t)kn * 4096);
            bh1 = *(const f16x8*)(q1h + (size_t)kn * 4096 + 512);
            bl0 = *(const f16x8*)(q1l + (size_t)kn * 4096);
            bl1 = *(const f16x8*)(q1l + (size_t)kn * 4096 + 512);
            int koff = kst * 16 + q * 8;
            f16x8 ah = *(const f16x8*)(sm + ln31 * 264 + koff);
            f16x8 al = *(const f16x8*)(sm + 8448 + ln31 * 264 + koff);
            acc1a = __builtin_amdgcn_mfma_f32_32x32x16_f16(ah, ch0, acc1a, 0, 0, 0);
            acc1b = __builtin_amdgcn_mfma_f32_32x32x16_f16(ah, ch1, acc1b, 0, 0, 0);
            acc1a = __builtin_amdgcn_mfma_f32_32x32x16_f16(al, ch0, acc1a, 0, 0, 0);
            acc1b = __builtin_amdgcn_mfma_f32_32x32x16_f16(al, ch1, acc1b, 0, 0, 0);
            acc1a = __builtin_amdgcn_mfma_f32_32x32x16_f16(ah, cl0, acc1a, 0, 0, 0);
            acc1b = __builtin_amdgcn_mfma_f32_32x32x16_f16(ah, cl1, acc1b, 0, 0, 0);
        }
    }
    __syncthreads();  // all x reads done; region A becomes h1 planes

    // BN + ReLU epilogue; write h1 hi/lo planes (stride 264).
    {
#pragma unroll
        for (int nt = 0; nt < 2; ++nt) {
            int j = w * 64 + nt * 32 + ln31;
            float sc = gm[j] * rsqrtf(vr[j] + EPS_BN);
            float sh = (b1[j] - mu[j]) * sc + bt[j];
            const f32x16& a = nt ? acc1b : acc1a;
#pragma unroll
            for (int r = 0; r < 16; ++r) {
                int row = (r & 3) + 8 * (r >> 2) + 4 * q;
                float v = a[r] * sc + sh;
                v = v > 0.f ? v : 0.f;
                f16 h = (f16)v;
                sm[row * 264 + j]        = h;
                sm[8448 + row * 264 + j] = (f16)(v - (float)h);
            }
        }
    }
    __syncthreads();  // h1 ready

    // ================= Stage 2: h2 = ReLU(h1 @ W2^T + b2) ===================
    f32x16 acc2a = {};
    f32x16 acc2b = {};
    {
        const f16* q2h = p2h + (size_t)w * 512 + lane * 8;
        const f16* q2l = p2l + (size_t)w * 512 + lane * 8;
        f16x8 bh = *(const f16x8*)(q2h);
        f16x8 bl = *(const f16x8*)(q2l);
#pragma unroll 2
        for (int kst = 0; kst < 16; ++kst) {
            f16x8 cbh = bh, cbl = bl;
            int kn = (kst + 1) & 15;
            bh = *(const f16x8*)(q2h + (size_t)kn * 2048);
            bl = *(const f16x8*)(q2l + (size_t)kn * 2048);
            int koff = kst * 16 + q * 8;
            f16x8 ah = *(const f16x8*)(sm + ln31 * 264 + koff);
            f16x8 al = *(const f16x8*)(sm + 8448 + ln31 * 264 + koff);
            f32x16& acc = (kst & 1) ? acc2b : acc2a;
            acc = __builtin_amdgcn_mfma_f32_32x32x16_f16(ah, cbh, acc, 0, 0, 0);
            acc = __builtin_amdgcn_mfma_f32_32x32x16_f16(al, cbh, acc, 0, 0, 0);
            acc = __builtin_amdgcn_mfma_f32_32x32x16_f16(ah, cbl, acc, 0, 0, 0);
        }
    }
    __syncthreads();  // all h1 reads done -> region A reusable for h2

    // ReLU epilogue -> h2 planes aliased into region A (h2h@0, h2l@4352).
    {
        int j2 = w * 32 + ln31;
        float bias = b2[j2];
#pragma unroll
        for (int r = 0; r < 16; ++r) {
            int row = (r & 3) + 8 * (r >> 2) + 4 * q;
            float v = (acc2a[r] + acc2b[r]) + bias;
            v = v > 0.f ? v : 0.f;
            f16 h = (f16)v;
            sm[row * 136 + j2]        = h;
            sm[4352 + row * 136 + j2] = (f16)(v - (float)h);
        }
    }
    __syncthreads();  // h2 ready

    // ================= Stage 3: z = tanh(h2 @ W3^T + b3) ====================
    if (w < 2) {  // 64 output cols -> waves 0,1 only
        f32x16 acc3a = {};
        f32x16 acc3b = {};
        const f16* q3h = p3h + (size_t)w * 512 + lane * 8;
        const f16* q3l = p3l + (size_t)w * 512 + lane * 8;
        f16x8 bh = *(const f16x8*)(q3h);
        f16x8 bl = *(const f16x8*)(q3l);
#pragma unroll 2
        for (int ks = 0; ks < 8; ++ks) {
            f16x8 cbh = bh, cbl = bl;
            int kn = (ks + 1) & 7;
            bh = *(const f16x8*)(q3h + (size_t)kn * 1024);
            bl = *(const f16x8*)(q3l + (size_t)kn * 1024);
            f16x8 ah = *(const f16x8*)(sm + ln31 * 136 + ks * 16 + q * 8);
            f16x8 al = *(const f16x8*)(sm + 4352 + ln31 * 136 + ks * 16 + q * 8);
            f32x16& acc = (ks & 1) ? acc3b : acc3a;
            acc = __builtin_amdgcn_mfma_f32_32x32x16_f16(ah, cbh, acc, 0, 0, 0);
            acc = __builtin_amdgcn_mfma_f32_32x32x16_f16(al, cbh, acc, 0, 0, 0);
            acc = __builtin_amdgcn_mfma_f32_32x32x16_f16(ah, cbl, acc, 0, 0, 0);
        }
        int j3 = w * 32 + ln31;
        float bias = b3[j3];
#pragma unroll
        for (int r = 0; r < 16; ++r) {
            int row = (r & 3) + 8 * (r >> 2) + 4 * q;
            float zv = tanhf((acc3a[r] + acc3b[r]) + bias);
            f16 h = (f16)zv;
            size_t idx = (size_t)(r0 + row) * EMB_DIM + j3;
            Zh[idx] = h;
            Zl[idx] = (f16)(zv - (float)h);
        }
    }
}

// ---------------------------------------------------------------------------
// Kernel 2: MFMA argmin — R13/R16 DMA+dbuf structure with 64-CODE CHUNKS.
// 128 rows/block, 256 threads (4 waves), grid 512. Wave w owns row-tile w;
// consumes both ct2 of the shared chunk. Buffers 16KB each (8 frags x 512
// f16 x 2 planes), dbuf 32KB -> 4 blocks/CU = 4 waves/SIMD (VGPR 108 -> 16
// waves/CU allowed). Staging: per-lane GLOBAL gather of the chunk's 8
// fragments from the fragment-major pack; LDS dest lane-linear (required).
// Visit order (c64 asc, ct2 asc) == old (ch,ct) order; operand values,
// MFMA sequence, compare trajectory bit-identical -> absmax 0.
// score(r,c) = z_r.e_c - 0.5||e_c||^2, maximized == argmin distance.
// ---------------------------------------------------------------------------
__global__ __launch_bounds__(256) void k_argmin_mfma(
    const f16* __restrict__ Zh, const f16* __restrict__ Zl,
    const f16* __restrict__ cfh, const f16* __restrict__ cfl,
    const float* __restrict__ norms, int* __restrict__ out) {
    __shared__ __align__(16) f16 sm[16896];  // 33.8KB: buf b at b*8192 f16 (4KB H + 4KB L each... see map)
    // Buffer map (f16 units): buf b base = b*8192; H plane [0,4096), L plane
    // [4096,8192). Frag f_local at f_local*512 within its plane.
    const int tid  = threadIdx.x;
    const int lane = tid & 63;
    const int w    = tid >> 6;      // 0..3 = row-tile
    const int ln31 = lane & 31;
    const int q    = lane >> 5;
    const int r0   = blockIdx.x * 128;

    // z fragments: 8 x 16B per lane, straight from global (row-major Z).
    f16x8 ah[4], al[4];
#pragma unroll
    for (int ks = 0; ks < 4; ++ks) {
        size_t zoff = (size_t)(r0 + w * 32 + ln31) * EMB_DIM + ks * 16 + q * 8;
        ah[ks] = *(const f16x8*)(Zh + zoff);
        al[ks] = *(const f16x8*)(Zl + zoff);
    }

    float bv[16];
    int   bi[16];
#pragma unroll
    for (int i = 0; i < 16; ++i) { bv[i] = -3.4e38f; bi[i] = 0; }

    // Stage chunk C64 (64 codes) into buffer B. 512 x 16B units per plane:
    // unit u = it*256+tid; f_local = u>>6 (ks = f_local>>1, ct2 = f_local&1);
    // global frag = (C64>>1)*16 + ks*4 + (C64&1)*2 + ct2 (fragment-major pack).
    // LDS dest linear in u (lane-linear per wave, as global_load_lds needs);
    // global src per-lane gather.
#define STAGE(C64, B) do {                                                    \
        _Pragma("unroll")                                                     \
        for (int it_ = 0; it_ < 2; ++it_) {                                   \
            int u_  = it_ * 256 + tid;                                        \
            int fl_ = u_ >> 6;                                                \
            int fg_ = ((C64) >> 1) * 16 + (fl_ >> 1) * 4 + ((C64) & 1) * 2    \
                      + (fl_ & 1);                                            \
            size_t so_ = (size_t)fg_ * 512 + (u_ & 63) * 8;                   \
            int    do_ = (B) * 8192 + u_ * 8;                                 \
            __builtin_amdgcn_global_load_lds(                                 \
                (const __attribute__((address_space(1))) void*)(cfh + so_),   \
                (__attribute__((address_space(3))) void*)(sm + do_),          \
                16, 0, 0);                                                    \
            __builtin_amdgcn_global_load_lds(                                 \
                (const __attribute__((address_space(1))) void*)(cfl + so_),   \
                (__attribute__((address_space(3))) void*)(sm + do_ + 4096),   \
                16, 0, 0);                                                    \
        }                                                                     \
    } while (0)

    STAGE(0, 0);
    __syncthreads();   // prologue: buf0 ready (barrier drains vmcnt)

#pragma unroll 1
    for (int c64 = 0; c64 < 64; ++c64) {
        int b = c64 & 1;
        if (c64 + 1 < 64) STAGE(c64 + 1, b ^ 1);   // DMA lands under compute
        const f16* ebh = sm + b * 8192;
        const f16* ebl = sm + b * 8192 + 4096;
#pragma unroll
        for (int ct2 = 0; ct2 < 2; ++ct2) {
            f16x8 bh[4], bl[4];
#pragma unroll
            for (int ks = 0; ks < 4; ++ks) {
                int off = (ks * 2 + ct2) * 512 + lane * 8;
                bh[ks] = *(const f16x8*)(ebh + off);
                bl[ks] = *(const f16x8*)(ebl + off);
            }
            f32x16 acc0 = {};
            f32x16 acc1 = {};
#pragma unroll
            for (int ks = 0; ks < 4; ks += 2) {
                acc0 = __builtin_amdgcn_mfma_f32_32x32x16_f16(ah[ks],     bh[ks],     acc0, 0, 0, 0);
                acc1 = __builtin_amdgcn_mfma_f32_32x32x16_f16(ah[ks + 1], bh[ks + 1], acc1, 0, 0, 0);
                acc0 = __builtin_amdgcn_mfma_f32_32x32x16_f16(al[ks],     bh[ks],     acc0, 0, 0, 0);
                acc1 = __builtin_amdgcn_mfma_f32_32x32x16_f16(al[ks + 1], bh[ks + 1], acc1, 0, 0, 0);
                acc0 = __builtin_amdgcn_mfma_f32_32x32x16_f16(ah[ks],     bl[ks],     acc0, 0, 0, 0);
                acc1 = __builtin_amdgcn_mfma_f32_32x32x16_f16(ah[ks + 1], bl[ks + 1], acc1, 0, 0, 0);
            }
            int   col = c64 * 64 + ct2 * 32 + ln31;
            float nv  = norms[col];
#pragma unroll
            for (int r = 0; r < 16; ++r) {
                float t  = (acc0[r] + acc1[r]) - nv;
                bool  gt = t > bv[r];
                bv[r] = gt ? t : bv[r];
                bi[r] = gt ? col : bi[r];
            }
        }
        __syncthreads();  // drains vmcnt: buf^1 ready, buf free for re-stage
    }
#undef STAGE

    // ---- cross-lane reduction over 32 code-columns ------------------------
    float* redv = (float*)sm;                // [128][33] f32, bytes [0,16896)
    int*   redi = (int*)sm + 4224;           // [128][33] i32, bytes [16896,33792)
#pragma unroll
    for (int r = 0; r < 16; ++r) {
        int row = w * 32 + (r & 3) + 8 * (r >> 2) + 4 * q;
        redv[row * 33 + ln31] = bv[r];
        redi[row * 33 + ln31] = bi[r];
    }
    __syncthreads();
    if (tid < 128) {
        float v  = redv[tid * 33];
        int   ix = redi[tid * 33];
#pragma unroll
        for (int j = 1; j < 32; ++j) {
            float vj = redv[tid * 33 + j];
            int   ij = redi[tid * 33 + j];
            if (vj > v || (vj == v && ij < ix)) { v = vj; ix = ij; }
        }
        out[r0 + tid] = ix;
    }
}

// ---------------------------------------------------------------------------
extern "C" void kernel_launch(void* const* d_in, const int* in_sizes, int n_in,
                              void* d_out, int out_size, void* d_ws, size_t ws_size,
                              hipStream_t stream) {
    (void)n_in; (void)out_size; (void)ws_size;
    const float* x  = (const float*)d_in[0];
    const float* W1 = (const float*)d_in[1];
    const float* b1 = (const float*)d_in[2];
    const float* gm = (const float*)d_in[3];
    const float* bt = (const float*)d_in[4];
    const float* mu = (const float*)d_in[5];
    const float* vr = (const float*)d_in[6];
    const float* W2 = (const float*)d_in[7];
    const float* b2 = (const float*)d_in[8];
    const float* W3 = (const float*)d_in[9];
    const float* b3 = (const float*)d_in[10];
    const float* cb = (const float*)d_in[11];

    // Workspace layout (~17.4 MB) — same offsets as R6/R7
    char* ws = (char*)d_ws;
    float* norms = (float*)ws;                    // 16 KB
    f16* cfh = (f16*)(ws + 16384);                // 512 KB (cb frags hi)
    f16* cfl = (f16*)(ws + 540672);               // 512 KB (cb frags lo)
    f16* p1h = (f16*)(ws + 1064960);              // 128 KB
    f16* p1l = (f16*)(ws + 1196032);              // 128 KB
    f16* p2h = (f16*)(ws + 1327104);              // 64 KB
    f16* p2l = (f16*)(ws + 1392640);              // 64 KB
    f16* p3h = (f16*)(ws + 1458176);              // 16 KB
    f16* p3l = (f16*)(ws + 1474560);              // 16 KB
    f16* Zh  = (f16*)(ws + 1490944);              // 8 MB
    f16* Zl  = (f16*)(ws + 9879552);              // 8 MB
    int* out = (int*)d_out;

    const int B = in_sizes[0] / IN_DIM;  // 65536

    k_norms<<<K_CODES / 256, 256, 0, stream>>>(cb, norms);
    k_prep<<<180, 256, 0, stream>>>(W1, W2, W3, cb, p1h, p1l, p2h, p2l,
                                    p3h, p3l, cfh, cfl);
    k_encoder_mfma<<<B / 32, 256, 0, stream>>>(x, p1h, p1l, p2h, p2l, p3h, p3l,
                                               b1, gm, bt, mu, vr, b2, b3, Zh, Zl);
    k_argmin_mfma<<<B / 128, 256, 0, stream>>>(Zh, Zl, cfh, cfl, norms, out);
}

// Round 14
// 269.362 us; speedup vs baseline: 1.0363x; 1.0363x over previous
//
#include <hip/hip_runtime.h>

// Problem constants (fixed by reference)
#define IN_DIM  256
#define HID_DIM 256
#define H2_DIM  128
#define EMB_DIM 64
#define K_CODES 4096
#define EPS_BN  1e-5f

// History: R5 hi/lo-split MFMA argmin 205us. R6 fused encoder 295. R9
// barrier-free stream 126. R13 global_load_lds DMA + dbuf (128-code
// chunks, 64KB LDS) 119us. R15 FAILED (absmax 1156): folding -nv into
// MFMA C-init reorders score rounding -> flips near-ties in the DISCRETE
// argmin. RULE: never reorder score arithmetic (acc from 0, subtract nv
// in fp32 after, acc0+acc1 pairing). R16: R13 verbatim + encoder
// h2-aliasing: 267.2us BEST (argmin 116.7, MfmaUtil+VALUBusy ~97% =
// issue-saturated). R17 norms-in-LDS NULL. R18 64-code chunks REGRESS
// (grid 512 caps 2 blocks/CU regardless of LDS — lowering LDS can't add
// blocks; doubled barriers hurt). R12 already showed grid 1024 trips the
// VGPR+AGPR wave cap. Ten argmin variants bracket 116.7-135.
// R19: LOCK IN R16. R20: resubmit (R19 bench was an infra failure —
// container died twice; no kernel signal).

typedef _Float16 f16;
typedef _Float16 f16x4 __attribute__((ext_vector_type(4)));
typedef _Float16 f16x8 __attribute__((ext_vector_type(8)));
typedef float    f32x16 __attribute__((ext_vector_type(16)));

// ---------------------------------------------------------------------------
// Kernel 0a: half squared norms of codebook rows: norms[c] = 0.5*||e_c||^2
// ---------------------------------------------------------------------------
__global__ __launch_bounds__(256) void k_norms(const float* __restrict__ cb,
                                               float* __restrict__ norms) {
    int c = blockIdx.x * 256 + threadIdx.x;
    const float4* row = reinterpret_cast<const float4*>(cb + (size_t)c * EMB_DIM);
    float s = 0.f;
#pragma unroll
    for (int i = 0; i < EMB_DIM / 4; ++i) {
        float4 v = row[i];
        s += v.x * v.x + v.y * v.y + v.z * v.z + v.w * v.w;
    }
    norms[c] = 0.5f * s;
}

// ---------------------------------------------------------------------------
// Kernel 0b: fragment-major hi/lo packer.
// A fragment = 512 f16 = what one wave loads for one (k16-step, 32-col-tile):
//   P[f*512 + l*8 + j] = W[ct*32 + (l&31)][k0 + (l>>5)*8 + j]
// f16x8 unit index t (one thread each), 46080 total:
//   [0,8192)      W1 [256][256]: f = kst*8 + ct   (kst<16, ct<8)
//   [8192,12288)  W2 [128][256]: f = kst*4 + ct   (kst<16, ct<4)
//   [12288,13312) W3 [ 64][128]: f = ks*2  + ct   (ks<8, ct<2)
//   [13312,46080) cb [4096][64]: f = (ch*4+ks)*4+ct (ch<32, ks<4, ct<4)
// ---------------------------------------------------------------------------
__global__ __launch_bounds__(256) void k_prep(
    const float* __restrict__ W1, const float* __restrict__ W2,
    const float* __restrict__ W3, const float* __restrict__ cb,
    f16* __restrict__ p1h, f16* __restrict__ p1l,
    f16* __restrict__ p2h, f16* __restrict__ p2l,
    f16* __restrict__ p3h, f16* __restrict__ p3l,
    f16* __restrict__ cfh, f16* __restrict__ cfl) {
    int t = blockIdx.x * 256 + threadIdx.x;   // < 46080
    const float* src; f16 *dh, *dl; int tt, row, k0, K;
    if (t < 8192) {
        tt = t; int f = tt >> 6, l = tt & 63;
        int ct = f & 7, kst = f >> 3;
        row = ct * 32 + (l & 31); k0 = kst * 16 + (l >> 5) * 8;
        src = W1; K = IN_DIM; dh = p1h; dl = p1l;
    } else if (t < 12288) {
        tt = t - 8192; int f = tt >> 6, l = tt & 63;
        int ct = f & 3, kst = f >> 2;
        row = ct * 32 + (l & 31); k0 = kst * 16 + (l >> 5) * 8;
        src = W2; K = HID_DIM; dh = p2h; dl = p2l;
    } else if (t < 13312) {
        tt = t - 12288; int f = tt >> 6, l = tt & 63;
        int ct = f & 1, ks = f >> 1;
        row = ct * 32 + (l & 31); k0 = ks * 16 + (l >> 5) * 8;
        src = W3; K = H2_DIM; dh = p3h; dl = p3l;
    } else {
        tt = t - 13312; int f = tt >> 6, l = tt & 63;
        int ct = f & 3, ks = (f >> 2) & 3, ch = f >> 4;
        row = ch * 128 + ct * 32 + (l & 31); k0 = ks * 16 + (l >> 5) * 8;
        src = cb; K = EMB_DIM; dh = cfh; dl = cfl;
    }
    const float* s = src + (size_t)row * K + k0;
    f16x8 hv, lv;
#pragma unroll
    for (int j = 0; j < 8; ++j) {
        float v = s[j];
        f16 h = (f16)v;
        hv[j] = h;
        lv[j] = (f16)(v - (float)h);
    }
    *(f16x8*)(dh + (size_t)tt * 8) = hv;
    *(f16x8*)(dl + (size_t)tt * 8) = lv;
}

// ---------------------------------------------------------------------------
// Kernel 1: fused MFMA encoder. 32 rows/block, 256 threads (4 waves).
// All GEMMs as v_mfma_f32_32x32x16_f16, 3 passes (hh, lh, hl) per k-step.
// A-frags from LDS; B-frags streamed from fragment-major global with 1-deep
// register prefetch. h2 planes ALIASED into region A after stage-2 k-loop
// (extra barrier; bit-identical values) -> LDS 33KB -> 4 blocks/CU.
// LDS map: region A [0,16896) f16: xh/h1h@0, xl/h1l@8448 (stride 264);
//          after stage-2 k-loop: h2h@0, h2l@4352 (stride 136).
// ---------------------------------------------------------------------------
__global__ __launch_bounds__(256) void k_encoder_mfma(
    const float* __restrict__ x,
    const f16* __restrict__ p1h, const f16* __restrict__ p1l,
    const f16* __restrict__ p2h, const f16* __restrict__ p2l,
    const f16* __restrict__ p3h, const f16* __restrict__ p3l,
    const float* __restrict__ b1,
    const float* __restrict__ gm, const float* __restrict__ bt,
    const float* __restrict__ mu, const float* __restrict__ vr,
    const float* __restrict__ b2, const float* __restrict__ b3,
    f16* __restrict__ Zh, f16* __restrict__ Zl) {
    __shared__ __align__(16) f16 sm[16896];   // 33 KB -> 4 blocks/CU
    const int tid  = threadIdx.x;
    const int lane = tid & 63;
    const int w    = tid >> 6;
    const int ln31 = lane & 31;
    const int q    = lane >> 5;
    const int r0   = blockIdx.x * 32;

    // ---- stage x [32 rows][256 k] fp32 -> hi/lo f16 planes, once ----------
#pragma unroll
    for (int it = 0; it < 8; ++it) {
        int i = it * 256 + tid;              // float4 id, 2048 total
        int row = i >> 6, c4 = (i & 63) * 4;
        float4 v = *reinterpret_cast<const float4*>(
            x + (size_t)(r0 + row) * IN_DIM + c4);
        f16x4 hv, lv;
        hv[0] = (f16)v.x; lv[0] = (f16)(v.x - (float)hv[0]);
        hv[1] = (f16)v.y; lv[1] = (f16)(v.y - (float)hv[1]);
        hv[2] = (f16)v.z; lv[2] = (f16)(v.z - (float)hv[2]);
        hv[3] = (f16)v.w; lv[3] = (f16)(v.w - (float)hv[3]);
        *(f16x4*)(sm + row * 264 + c4)        = hv;
        *(f16x4*)(sm + 8448 + row * 264 + c4) = lv;
    }
    __syncthreads();

    // ================= Stage 1: h1 = BN+ReLU(x @ W1^T) ======================
    f32x16 acc1a = {};
    f32x16 acc1b = {};
    {
        const f16* q1h = p1h + (size_t)(2 * w) * 512 + lane * 8;
        const f16* q1l = p1l + (size_t)(2 * w) * 512 + lane * 8;
        f16x8 bh0 = *(const f16x8*)(q1h);
        f16x8 bh1 = *(const f16x8*)(q1h + 512);
        f16x8 bl0 = *(const f16x8*)(q1l);
        f16x8 bl1 = *(const f16x8*)(q1l + 512);
#pragma unroll 2
        for (int kst = 0; kst < 16; ++kst) {
            f16x8 ch0 = bh0, ch1 = bh1, cl0 = bl0, cl1 = bl1;
            int kn = (kst + 1) & 15;  // wrap: last prefetch redundant, harmless
            bh0 = *(const f16x8*)(q1h + (size_t)kn * 4096);
            bh1 = *(const f16x8*)(q1h + (size_t)kn * 4096 + 512);
            bl0 = *(const f16x8*)(q1l + (size_t)kn * 4096);
            bl1 = *(const f16x8*)(q1l + (size_t)kn * 4096 + 512);
            int koff = kst * 16 + q * 8;
            f16x8 ah = *(const f16x8*)(sm + ln31 * 264 + koff);
            f16x8 al = *(const f16x8*)(sm + 8448 + ln31 * 264 + koff);
            acc1a = __builtin_amdgcn_mfma_f32_32x32x16_f16(ah, ch0, acc1a, 0, 0, 0);
            acc1b = __builtin_amdgcn_mfma_f32_32x32x16_f16(ah, ch1, acc1b, 0, 0, 0);
            acc1a = __builtin_amdgcn_mfma_f32_32x32x16_f16(al, ch0, acc1a, 0, 0, 0);
            acc1b = __builtin_amdgcn_mfma_f32_32x32x16_f16(al, ch1, acc1b, 0, 0, 0);
            acc1a = __builtin_amdgcn_mfma_f32_32x32x16_f16(ah, cl0, acc1a, 0, 0, 0);
            acc1b = __builtin_amdgcn_mfma_f32_32x32x16_f16(ah, cl1, acc1b, 0, 0, 0);
        }
    }
    __syncthreads();  // all x reads done; region A becomes h1 planes

    // BN + ReLU epilogue; write h1 hi/lo planes (stride 264).
    {
#pragma unroll
        for (int nt = 0; nt < 2; ++nt) {
            int j = w * 64 + nt * 32 + ln31;
            float sc = gm[j] * rsqrtf(vr[j] + EPS_BN);
            float sh = (b1[j] - mu[j]) * sc + bt[j];
            const f32x16& a = nt ? acc1b : acc1a;
#pragma unroll
            for (int r = 0; r < 16; ++r) {
                int row = (r & 3) + 8 * (r >> 2) + 4 * q;
                float v = a[r] * sc + sh;
                v = v > 0.f ? v : 0.f;
                f16 h = (f16)v;
                sm[row * 264 + j]        = h;
                sm[8448 + row * 264 + j] = (f16)(v - (float)h);
            }
        }
    }
    __syncthreads();  // h1 ready

    // ================= Stage 2: h2 = ReLU(h1 @ W2^T + b2) ===================
    f32x16 acc2a = {};
    f32x16 acc2b = {};
    {
        const f16* q2h = p2h + (size_t)w * 512 + lane * 8;
        const f16* q2l = p2l + (size_t)w * 512 + lane * 8;
        f16x8 bh = *(const f16x8*)(q2h);
        f16x8 bl = *(const f16x8*)(q2l);
#pragma unroll 2
        for (int kst = 0; kst < 16; ++kst) {
            f16x8 cbh = bh, cbl = bl;
            int kn = (kst + 1) & 15;
            bh = *(const f16x8*)(q2h + (size_t)kn * 2048);
            bl = *(const f16x8*)(q2l + (size_t)kn * 2048);
            int koff = kst * 16 + q * 8;
            f16x8 ah = *(const f16x8*)(sm + ln31 * 264 + koff);
            f16x8 al = *(const f16x8*)(sm + 8448 + ln31 * 264 + koff);
            f32x16& acc = (kst & 1) ? acc2b : acc2a;
            acc = __builtin_amdgcn_mfma_f32_32x32x16_f16(ah, cbh, acc, 0, 0, 0);
            acc = __builtin_amdgcn_mfma_f32_32x32x16_f16(al, cbh, acc, 0, 0, 0);
            acc = __builtin_amdgcn_mfma_f32_32x32x16_f16(ah, cbl, acc, 0, 0, 0);
        }
    }
    __syncthreads();  // all h1 reads done -> region A reusable for h2

    // ReLU epilogue -> h2 planes aliased into region A (h2h@0, h2l@4352).
    {
        int j2 = w * 32 + ln31;
        float bias = b2[j2];
#pragma unroll
        for (int r = 0; r < 16; ++r) {
            int row = (r & 3) + 8 * (r >> 2) + 4 * q;
            float v = (acc2a[r] + acc2b[r]) + bias;
            v = v > 0.f ? v : 0.f;
            f16 h = (f16)v;
            sm[row * 136 + j2]        = h;
            sm[4352 + row * 136 + j2] = (f16)(v - (float)h);
        }
    }
    __syncthreads();  // h2 ready

    // ================= Stage 3: z = tanh(h2 @ W3^T + b3) ====================
    if (w < 2) {  // 64 output cols -> waves 0,1 only
        f32x16 acc3a = {};
        f32x16 acc3b = {};
        const f16* q3h = p3h + (size_t)w * 512 + lane * 8;
        const f16* q3l = p3l + (size_t)w * 512 + lane * 8;
        f16x8 bh = *(const f16x8*)(q3h);
        f16x8 bl = *(const f16x8*)(q3l);
#pragma unroll 2
        for (int ks = 0; ks < 8; ++ks) {
            f16x8 cbh = bh, cbl = bl;
            int kn = (ks + 1) & 7;
            bh = *(const f16x8*)(q3h + (size_t)kn * 1024);
            bl = *(const f16x8*)(q3l + (size_t)kn * 1024);
            f16x8 ah = *(const f16x8*)(sm + ln31 * 136 + ks * 16 + q * 8);
            f16x8 al = *(const f16x8*)(sm + 4352 + ln31 * 136 + ks * 16 + q * 8);
            f32x16& acc = (ks & 1) ? acc3b : acc3a;
            acc = __builtin_amdgcn_mfma_f32_32x32x16_f16(ah, cbh, acc, 0, 0, 0);
            acc = __builtin_amdgcn_mfma_f32_32x32x16_f16(al, cbh, acc, 0, 0, 0);
            acc = __builtin_amdgcn_mfma_f32_32x32x16_f16(ah, cbl, acc, 0, 0, 0);
        }
        int j3 = w * 32 + ln31;
        float bias = b3[j3];
#pragma unroll
        for (int r = 0; r < 16; ++r) {
            int row = (r & 3) + 8 * (r >> 2) + 4 * q;
            float zv = tanhf((acc3a[r] + acc3b[r]) + bias);
            f16 h = (f16)zv;
            size_t idx = (size_t)(r0 + row) * EMB_DIM + j3;
            Zh[idx] = h;
            Zl[idx] = (f16)(zv - (float)h);
        }
    }
}

// ---------------------------------------------------------------------------
// Kernel 2: MFMA argmin — R13/R16 structure VERBATIM (best measured 116.7us;
// score accumulation order is part of the verified numeric contract).
// 128 rows/block, 256 threads (4 waves), grid 512. Wave w owns row-tile w;
// consumes all 4 ct from the shared LDS chunk. Double-buffered
// global_load_lds DMA: stage(ch+1) issued BEFORE compute(ch); barrier
// drains vmcnt. score(r,c) = z_r.e_c - 0.5||e_c||^2, maximized == argmin.
// ---------------------------------------------------------------------------
__global__ __launch_bounds__(256) void k_argmin_mfma(
    const f16* __restrict__ Zh, const f16* __restrict__ Zl,
    const f16* __restrict__ cfh, const f16* __restrict__ cfl,
    const float* __restrict__ norms, int* __restrict__ out) {
    __shared__ __align__(16) f16 sm[32768];  // 64KB: buf b at b*16384 (H), +8192 (L)
    const int tid  = threadIdx.x;
    const int lane = tid & 63;
    const int w    = tid >> 6;      // 0..3 = row-tile
    const int ln31 = lane & 31;
    const int q    = lane >> 5;
    const int r0   = blockIdx.x * 128;

    // z fragments: 8 x 16B per lane, straight from global (row-major Z).
    f16x8 ah[4], al[4];
#pragma unroll
    for (int ks = 0; ks < 4; ++ks) {
        size_t zoff = (size_t)(r0 + w * 32 + ln31) * EMB_DIM + ks * 16 + q * 8;
        ah[ks] = *(const f16x8*)(Zh + zoff);
        al[ks] = *(const f16x8*)(Zl + zoff);
    }

    float bv[16];
    int   bi[16];
#pragma unroll
    for (int i = 0; i < 16; ++i) { bv[i] = -3.4e38f; bi[i] = 0; }

#define STAGE(CH, B) do {                                                     \
        const f16* sH_ = cfh + (size_t)(CH) * 8192;                           \
        const f16* sL_ = cfl + (size_t)(CH) * 8192;                           \
        f16* dH_ = sm + (B) * 16384;                                          \
        f16* dL_ = sm + (B) * 16384 + 8192;                                   \
        _Pragma("unroll")                                                     \
        for (int it_ = 0; it_ < 4; ++it_) {                                   \
            int off_ = (it_ * 256 + tid) * 8;                                 \
            __builtin_amdgcn_global_load_lds(                                 \
                (const __attribute__((address_space(1))) void*)(sH_ + off_),  \
                (__attribute__((address_space(3))) void*)(dH_ + off_),        \
                16, 0, 0);                                                    \
            __builtin_amdgcn_global_load_lds(                                 \
                (const __attribute__((address_space(1))) void*)(sL_ + off_),  \
                (__attribute__((address_space(3))) void*)(dL_ + off_),        \
                16, 0, 0);                                                    \
        }                                                                     \
    } while (0)

    STAGE(0, 0);
    __syncthreads();   // prologue: buf0 ready (barrier drains vmcnt)

#pragma unroll 1
    for (int ch = 0; ch < 32; ++ch) {
        int b = ch & 1;
        if (ch + 1 < 32) STAGE(ch + 1, b ^ 1);   // DMA lands under compute
        const f16* ebh = sm + b * 16384;
        const f16* ebl = sm + b * 16384 + 8192;
#pragma unroll 2
        for (int ct = 0; ct < 4; ++ct) {
            f16x8 bh[4], bl[4];
#pragma unroll
            for (int ks = 0; ks < 4; ++ks) {
                int off = (ks * 4 + ct) * 512 + lane * 8;
                bh[ks] = *(const f16x8*)(ebh + off);
                bl[ks] = *(const f16x8*)(ebl + off);
            }
            f32x16 acc0 = {};
            f32x16 acc1 = {};
#pragma unroll
            for (int ks = 0; ks < 4; ks += 2) {
                acc0 = __builtin_amdgcn_mfma_f32_32x32x16_f16(ah[ks],     bh[ks],     acc0, 0, 0, 0);
                acc1 = __builtin_amdgcn_mfma_f32_32x32x16_f16(ah[ks + 1], bh[ks + 1], acc1, 0, 0, 0);
                acc0 = __builtin_amdgcn_mfma_f32_32x32x16_f16(al[ks],     bh[ks],     acc0, 0, 0, 0);
                acc1 = __builtin_amdgcn_mfma_f32_32x32x16_f16(al[ks + 1], bh[ks + 1], acc1, 0, 0, 0);
                acc0 = __builtin_amdgcn_mfma_f32_32x32x16_f16(ah[ks],     bl[ks],     acc0, 0, 0, 0);
                acc1 = __builtin_amdgcn_mfma_f32_32x32x16_f16(ah[ks + 1], bl[ks + 1], acc1, 0, 0, 0);
            }
            int   col = ch * 128 + ct * 32 + ln31;
            float nv  = norms[col];
#pragma unroll
            for (int r = 0; r < 16; ++r) {
                float t  = (acc0[r] + acc1[r]) - nv;
                bool  gt = t > bv[r];
                bv[r] = gt ? t : bv[r];
                bi[r] = gt ? col : bi[r];
            }
        }
        __syncthreads();  // drains vmcnt: buf^1 ready, buf free for re-stage
    }
#undef STAGE

    // ---- cross-lane reduction over 32 code-columns ------------------------
    float* redv = (float*)sm;                // [128][33] f32, bytes [0,16896)
    int*   redi = (int*)sm + 4224;           // [128][33] i32, bytes [16896,33792)
#pragma unroll
    for (int r = 0; r < 16; ++r) {
        int row = w * 32 + (r & 3) + 8 * (r >> 2) + 4 * q;
        redv[row * 33 + ln31] = bv[r];
        redi[row * 33 + ln31] = bi[r];
    }
    __syncthreads();
    if (tid < 128) {
        float v  = redv[tid * 33];
        int   ix = redi[tid * 33];
#pragma unroll
        for (int j = 1; j < 32; ++j) {
            float vj = redv[tid * 33 + j];
            int   ij = redi[tid * 33 + j];
            if (vj > v || (vj == v && ij < ix)) { v = vj; ix = ij; }
        }
        out[r0 + tid] = ix;
    }
}

// ---------------------------------------------------------------------------
extern "C" void kernel_launch(void* const* d_in, const int* in_sizes, int n_in,
                              void* d_out, int out_size, void* d_ws, size_t ws_size,
                              hipStream_t stream) {
    (void)n_in; (void)out_size; (void)ws_size;
    const float* x  = (const float*)d_in[0];
    const float* W1 = (const float*)d_in[1];
    const float* b1 = (const float*)d_in[2];
    const float* gm = (const float*)d_in[3];
    const float* bt = (const float*)d_in[4];
    const float* mu = (const float*)d_in[5];
    const float* vr = (const float*)d_in[6];
    const float* W2 = (const float*)d_in[7];
    const float* b2 = (const float*)d_in[8];
    const float* W3 = (const float*)d_in[9];
    const float* b3 = (const float*)d_in[10];
    const float* cb = (const float*)d_in[11];

    // Workspace layout (~17.4 MB) — same offsets as R6/R7
    char* ws = (char*)d_ws;
    float* norms = (float*)ws;                    // 16 KB
    f16* cfh = (f16*)(ws + 16384);                // 512 KB (cb frags hi)
    f16* cfl = (f16*)(ws + 540672);               // 512 KB (cb frags lo)
    f16* p1h = (f16*)(ws + 1064960);              // 128 KB
    f16* p1l = (f16*)(ws + 1196032);              // 128 KB
    f16* p2h = (f16*)(ws + 1327104);              // 64 KB
    f16* p2l = (f16*)(ws + 1392640);              // 64 KB
    f16* p3h = (f16*)(ws + 1458176);              // 16 KB
    f16* p3l = (f16*)(ws + 1474560);              // 16 KB
    f16* Zh  = (f16*)(ws + 1490944);              // 8 MB
    f16* Zl  = (f16*)(ws + 9879552);              // 8 MB
    int* out = (int*)d_out;

    const int B = in_sizes[0] / IN_DIM;  // 65536

    k_norms<<<K_CODES / 256, 256, 0, stream>>>(cb, norms);
    k_prep<<<180, 256, 0, stream>>>(W1, W2, W3, cb, p1h, p1l, p2h, p2l,
                                    p3h, p3l, cfh, cfl);
    k_encoder_mfma<<<B / 32, 256, 0, stream>>>(x, p1h, p1l, p2h, p2l, p3h, p3l,
                                               b1, gm, bt, mu, vr, b2, b3, Zh, Zl);
    k_argmin_mfma<<<B / 128, 256, 0, stream>>>(Zh, Zl, cfh, cfl, norms, out);
}